// Round 5
// baseline (651.858 us; speedup 1.0000x reference)
//
#include <hip/hip_runtime.h>
#include <hip/hip_bf16.h>
#include <stdint.h>

typedef __attribute__((ext_vector_type(8))) short short8;
typedef __attribute__((ext_vector_type(4))) float floatx4;

#define MFMA32K(a, b, c) __builtin_amdgcn_mfma_f32_16x16x32_bf16(a, b, c, 0, 0, 0)

constexpr int N_Q  = 8192;
constexpr int M_KV = 8192;
constexpr int DMID = 128;
constexpr int DV   = 256;

__device__ __forceinline__ unsigned short f2bf(float x) {
    unsigned u = __float_as_uint(x);
    u += 0x7fffu + ((u >> 16) & 1u);
    return (unsigned short)(u >> 16);
}

__device__ __forceinline__ short8 cvt_f8_bf8(float4 a, float4 b) {
    short8 r;
    r[0] = (short)f2bf(a.x); r[1] = (short)f2bf(a.y);
    r[2] = (short)f2bf(a.z); r[3] = (short)f2bf(a.w);
    r[4] = (short)f2bf(b.x); r[5] = (short)f2bf(b.y);
    r[6] = (short)f2bf(b.z); r[7] = (short)f2bf(b.w);
    return r;
}

// barrier that drains ONLY LDS ops (ds_write visibility), never vmcnt:
// single asm block so the compiler cannot separate the wait from the barrier
// or move memory ops across ("memory" clobber = full compiler fence).
__device__ __forceinline__ void lgkm_barrier() {
    asm volatile("s_waitcnt lgkmcnt(0)\n\ts_barrier" ::: "memory");
}

// nonzero-byte -> 4-bit mask (bit i = byte i != 0)
__device__ __forceinline__ unsigned nz4(unsigned x) {
    unsigned nz = (((x & 0x7f7f7f7fu) + 0x7f7f7f7fu) | x) & 0x80808080u;
    unsigned a = (nz >> 7) & 0x01010101u;
    return (a * 0x01020408u) >> 24;
}

// ---------------------------------------------------------------------------
// Projections: dst[row] = src[row] @ W^T + bias, bf16, 16B-unit rotation
// within the row: unit' = (unit + row) & 15.
// ---------------------------------------------------------------------------
__global__ __launch_bounds__(256) void proj_kernel(
    const float* __restrict__ main_feat, const float* __restrict__ Wq, const float* __restrict__ bq,
    const float* __restrict__ other_feat, const float* __restrict__ Wk, const float* __restrict__ bk,
    unsigned short* __restrict__ Qw, unsigned short* __restrict__ Kw)
{
    const float* src;  const float* W;  const float* bias;  unsigned short* dst;
    if (blockIdx.y == 0) { src = main_feat;  W = Wq; bias = bq; dst = Qw; }
    else                 { src = other_feat; W = Wk; bias = bk; dst = Kw; }

    const int wave = threadIdx.x >> 6, lane = threadIdx.x & 63;
    const int n = lane & 15, quad = lane >> 4;
    const int row0 = blockIdx.x * 64 + wave * 16;

    short8 a[8];
    const float* ap = src + (size_t)(row0 + n) * 256 + quad * 8;
#pragma unroll
    for (int ks = 0; ks < 8; ++ks) {
        float4 x0 = *(const float4*)(ap + ks * 32);
        float4 x1 = *(const float4*)(ap + ks * 32 + 4);
        a[ks] = cvt_f8_bf8(x0, x1);
    }

    floatx4 acc[8];
#pragma unroll
    for (int nt = 0; nt < 8; ++nt) acc[nt] = floatx4{0.f, 0.f, 0.f, 0.f};

#pragma unroll
    for (int nt = 0; nt < 8; ++nt) {
        const float* wp = W + (size_t)(nt * 16 + n) * 256 + quad * 8;
#pragma unroll
        for (int ks = 0; ks < 8; ++ks) {
            float4 w0 = *(const float4*)(wp + ks * 32);
            float4 w1 = *(const float4*)(wp + ks * 32 + 4);
            short8 b = cvt_f8_bf8(w0, w1);
            acc[nt] = MFMA32K(a[ks], b, acc[nt]);
        }
    }

#pragma unroll
    for (int nt = 0; nt < 8; ++nt) {
        float bb = bias[nt * 16 + n];
#pragma unroll
        for (int reg = 0; reg < 4; ++reg) {
            int r = row0 + quad * 4 + reg;
            int c = nt * 16 + n;
            int phys = ((((c >> 3) + r) & 15) << 3) | (c & 7);
            dst[(size_t)r * DMID + phys] = f2bf(acc[nt][reg] + bb);
        }
    }
}

// ---------------------------------------------------------------------------
// Vt[d][col(m)] = fix[m] * other[m][d]; col = pc-permutation (kv=32e+16s+4q+j
// -> pc=32e+8q+4s+j) composed with 16B-unit rotation by d per 64-col group.
// ---------------------------------------------------------------------------
__global__ __launch_bounds__(256) void build_vt_kernel(
    const float* __restrict__ other_feat, const float* __restrict__ fix_feat,
    unsigned short* __restrict__ Vt)
{
    __shared__ unsigned short tile[64 * 72];
    const int t = threadIdx.x;
    const int m0 = blockIdx.x * 64, d0 = blockIdx.y * 64;

#pragma unroll
    for (int r = 0; r < 4; ++r) {
        int idx = r * 256 + t;
        int ml = idx >> 4, dl4 = (idx & 15) * 4;
        float4 v = *(const float4*)(other_feat + (size_t)(m0 + ml) * 256 + d0 + dl4);
        float f = fix_feat[m0 + ml];
        tile[(dl4 + 0) * 72 + ml] = f2bf(v.x * f);
        tile[(dl4 + 1) * 72 + ml] = f2bf(v.y * f);
        tile[(dl4 + 2) * 72 + ml] = f2bf(v.z * f);
        tile[(dl4 + 3) * 72 + ml] = f2bf(v.w * f);
    }
    __syncthreads();
#pragma unroll
    for (int r = 0; r < 8; ++r) {
        int dl = r * 8 + (t >> 5);
        int d = d0 + dl;
        int ml = (t & 31) * 2;
        int e = ml >> 5, s = (ml >> 4) & 1, q = (ml >> 2) & 3, j = ml & 3;
        int pc = e * 32 + q * 8 + s * 4 + j;
        int phys = ((((pc >> 3) + d) & 7) << 3) | (pc & 7);
        unsigned int v0 = tile[dl * 72 + ml];
        unsigned int v1 = tile[dl * 72 + ml + 1];
        *(unsigned int*)(Vt + (size_t)d * M_KV + m0 + phys) = v0 | (v1 << 16);
    }
}

// ---------------------------------------------------------------------------
// Flash attention body — counted-wait pipeline (no vmcnt-draining barriers):
// K/Vt/mask are REGISTER-staged one iteration ahead (global->reg issued in
// iter it-1, consumed at top of iter it -> full-iteration latency cover with
// compiler-managed counted vmcnt at each use). LDS cross-wave sync uses raw
// s_barrier preceded by lgkmcnt(0) only (ds_write drain, ~tens of cycles) —
// the HBM mask stream stays in flight across barriers.
// Per-iteration schedule (2 barriers, same LDS layout/addresses as the old
// global_load_lds path: dst = uniform base + lane*16B):
//   alpha: lgkm+bar  -> VtW(it); compress(it); issue VtL/ML(it+1), KW(it+1),
//          KL(it+2); QK(it); softmax
//   beta:  lgkm+bar  -> PV(it)
// ESZ = mask element size (4: int32/f32 nonzero; 1: bool/uint8), chosen by
// in-device dtype detection in the caller.
// BM=128, K double-buffered, Vt single-buffered, S^T formulation,
// all-16x16x32 MFMA, pc-permuted Vt, no online max. LDS 64 KB -> 2 blk/CU.
// ---------------------------------------------------------------------------
template<int ESZ>
__device__ __forceinline__ void flash_body(
    const unsigned short* __restrict__ Qw, const unsigned short* __restrict__ Kw,
    const unsigned short* __restrict__ Vt, const unsigned int* __restrict__ mask,
    unsigned short* __restrict__ Opart, float* __restrict__ Lpart,
    int nsplit, int lgNs,
    unsigned short* k_lds /* 2 x 64 x 128 */, unsigned short* vt_lds /* 256 x 64 */)
{
    const int L = blockIdx.x + gridDim.x * blockIdx.y;
    const int ly = L & (nsplit - 1);      // L&7 == XCD id under round-robin
    const int lx = L >> lgNs;             // -> per-XCD L2-resident K/V chunk
    const int chunkLen = M_KV >> lgNs;
    const int mBeg = ly * chunkLen;
    const int tid = threadIdx.x;
    const int wave = tid >> 6, lane = tid & 63, n = lane & 15, quad = lane >> 4;
    const int qrow0 = lx * 128 + wave * 32;
    constexpr float SC = 0.08838834764831845f * 1.4426950408889634f; // scale*log2(e)

    // Q fragments (rotated layout: unit' = (unit + row) & 15)
    short8 qf[2][4];
#pragma unroll
    for (int qt = 0; qt < 2; ++qt)
#pragma unroll
        for (int db = 0; db < 4; ++db) {
            int row = qrow0 + qt * 16 + n;
            int phys = (db * 4 + quad + row) & 15;
            qf[qt][db] = *(const short8*)(Qw + (size_t)row * DMID + phys * 8);
        }

    floatx4 Oacc[2][16];
#pragma unroll
    for (int qt = 0; qt < 2; ++qt)
#pragma unroll
        for (int dt = 0; dt < 16; ++dt) Oacc[qt][dt] = floatx4{0.f, 0.f, 0.f, 0.f};

    float lrow[2] = {0.f, 0.f};

    // staging invariants: per-lane GLOBAL source addresses identical to the
    // old gl_lds16 pattern; LDS dest = uniform base + lane*16B, made explicit.
    const unsigned short* kg = Kw + (size_t)(wave * 4 + (lane >> 4)) * DMID + (lane & 15) * 8;
    const unsigned short* vg = Vt + (size_t)(wave * 8 + (lane >> 3)) * M_KV + (lane & 7) * 8;
    const int kw_idx = wave * 512 + lane * 8;   // + r*2048 (+ buf*8192), shorts
    const int vw_idx = wave * 512 + lane * 8;   // + r*2048, shorts
    const int kqn = quad + n;

    // register staging (issued one iteration ahead; compiler inserts counted
    // vmcnt at the consuming ds_write/compress — never a vmcnt(0) barrier)
    uint4 kreg[4], vreg[8];
    uint4    mv4[2][4];   // ESZ==4: 16 elems/lane (cols m0+kvt*16+quad*4+j)
    unsigned mv1[2][4];   // ESZ==1: same cols, 4 bytes per dword

    auto load_K = [&](int m0l) {
#pragma unroll
        for (int r = 0; r < 4; ++r)
            kreg[r] = *(const uint4*)(kg + (size_t)(m0l + r * 16) * DMID);
    };
    auto load_Vt = [&](int m0l) {
#pragma unroll
        for (int r = 0; r < 8; ++r)
            vreg[r] = *(const uint4*)(vg + (size_t)(r * 32) * M_KV + m0l);
    };
    auto load_mask = [&](int m0l) {
#pragma unroll
        for (int qt = 0; qt < 2; ++qt) {
            const size_t row = (size_t)(qrow0 + qt * 16 + n);
            if constexpr (ESZ == 4) {
                const unsigned* mp = mask + row * M_KV + m0l + quad * 4;
#pragma unroll
                for (int kvt = 0; kvt < 4; ++kvt)
                    mv4[qt][kvt] = *(const uint4*)(mp + kvt * 16);
            } else {
                const unsigned* mp = mask + row * (M_KV / 4) + (m0l >> 2) + quad;
#pragma unroll
                for (int kvt = 0; kvt < 4; ++kvt)
                    mv1[qt][kvt] = mp[kvt * 4];
            }
        }
    };
    auto store_K = [&](int buf) {
#pragma unroll
        for (int r = 0; r < 4; ++r)
            *(uint4*)&k_lds[buf * 8192 + kw_idx + r * 2048] = kreg[r];
    };
    auto store_Vt = [&]() {
#pragma unroll
        for (int r = 0; r < 8; ++r)
            *(uint4*)&vt_lds[vw_idx + r * 2048] = vreg[r];
    };

    const int iters = chunkLen / 64;

    // prologue: K(0)->LDS buf0; prefetch K(1), Vt(0), mask(0) into regs
    load_K(mBeg);
    store_K(0);
    if (iters > 1) load_K(mBeg + 64);
    load_Vt(mBeg);
    load_mask(mBeg);

    for (int it = 0; it < iters; ++it) {
        const int m0 = mBeg + it * 64;
        const unsigned short* kbuf = k_lds + (it & 1) * 8192;

        lgkm_barrier();   // alpha: KW(it) visible; PV(it-1) done with vt_lds

        // Vt(it): regs -> LDS (counted vmcnt on vreg, issued in it-1)
        store_Vt();

        // compress mask regs -> 16 predicate bits per lane (bit kvt*4+j)
        unsigned wq[2];
#pragma unroll
        for (int qt = 0; qt < 2; ++qt) {
            unsigned b = 0;
            if constexpr (ESZ == 4) {
#pragma unroll
                for (int kvt = 0; kvt < 4; ++kvt) {
                    const unsigned* c = (const unsigned*)&mv4[qt][kvt];
#pragma unroll
                    for (int j = 0; j < 4; ++j)
                        b |= (c[j] != 0u ? 1u : 0u) << (kvt * 4 + j);
                }
            } else {
#pragma unroll
                for (int kvt = 0; kvt < 4; ++kvt)
                    b |= nz4(mv1[qt][kvt]) << (kvt * 4);
            }
            wq[qt] = b;
        }

        // issue next-iteration staging (full-iteration latency window)
        if (it + 1 < iters) {
            load_Vt(m0 + 64);
            load_mask(m0 + 64);
            store_K((it + 1) & 1);      // kreg(it+1) -> LDS (counted vmcnt)
        }
        if (it + 2 < iters) load_K(m0 + 128);

        // ---- S^T = K Q^T (kv = 16kvt + 4quad + reg, q = n) ----
        floatx4 ST[4][2];
        __builtin_amdgcn_s_setprio(1);
#pragma unroll
        for (int kvt = 0; kvt < 4; ++kvt) {
            const int rowoff = (kvt * 16 + n) * DMID;
            short8 a0 = *(const short8*)&kbuf[rowoff + (((kqn + 0) & 15) << 3)];
            short8 a1 = *(const short8*)&kbuf[rowoff + (((kqn + 4) & 15) << 3)];
            short8 a2 = *(const short8*)&kbuf[rowoff + (((kqn + 8) & 15) << 3)];
            short8 a3 = *(const short8*)&kbuf[rowoff + (((kqn + 12) & 15) << 3)];
#pragma unroll
            for (int qt = 0; qt < 2; ++qt) {
                floatx4 s = floatx4{0.f, 0.f, 0.f, 0.f};
                s = MFMA32K(a0, qf[qt][0], s);
                s = MFMA32K(a1, qf[qt][1], s);
                s = MFMA32K(a2, qf[qt][2], s);
                s = MFMA32K(a3, qf[qt][3], s);
                ST[kvt][qt] = s;
            }
        }
        __builtin_amdgcn_s_setprio(0);

        // ---- p = exp2(s*SC), 0 where masked; pack to A-frags ----
        short8 pf8[2][2];
#pragma unroll
        for (int qt = 0; qt < 2; ++qt) {
            const unsigned x = wq[qt];
            float lacc = 0.f;
#pragma unroll
            for (int kvt = 0; kvt < 4; ++kvt) {
                int e = kvt >> 1, s = kvt & 1;
                float p[4];
#pragma unroll
                for (int j = 0; j < 4; ++j) {
                    float v = __builtin_amdgcn_exp2f(ST[kvt][qt][j] * SC);
                    p[j] = ((x >> (kvt * 4 + j)) & 1u) ? 0.f : v;
                    lacc += p[j];
                }
                __hip_bfloat162 h0 = __float22bfloat162_rn(make_float2(p[0], p[1]));
                __hip_bfloat162 h1 = __float22bfloat162_rn(make_float2(p[2], p[3]));
                unsigned u0, u1;
                __builtin_memcpy(&u0, &h0, 4);
                __builtin_memcpy(&u1, &h1, 4);
                ((unsigned*)&pf8[qt][e])[s * 2 + 0] = u0;
                ((unsigned*)&pf8[qt][e])[s * 2 + 1] = u1;
            }
            lrow[qt] += lacc;
        }

        lgkm_barrier();   // beta: all waves' VtW(it) visible

        // ---- O += P V (rotated contiguous b128 from vt_lds) ----
        __builtin_amdgcn_s_setprio(1);
#pragma unroll
        for (int e = 0; e < 2; ++e) {
#pragma unroll
            for (int dt = 0; dt < 16; ++dt) {
                const int vb = (dt * 16 + n) * 64 + (((e * 4 + quad + n) & 7) << 3);
                short8 bv = *(const short8*)&vt_lds[vb];
                Oacc[0][dt] = MFMA32K(pf8[0][e], bv, Oacc[0][dt]);
                Oacc[1][dt] = MFMA32K(pf8[1][e], bv, Oacc[1][dt]);
            }
        }
        __builtin_amdgcn_s_setprio(0);
    }

    // ---- epilogue: bf16 partials + cross-quad l reduction ----
    const size_t obase = (size_t)ly * N_Q * DV;
#pragma unroll
    for (int qt = 0; qt < 2; ++qt)
#pragma unroll
        for (int dt = 0; dt < 16; ++dt)
#pragma unroll
            for (int reg = 0; reg < 4; ++reg) {
                int gr = qrow0 + qt * 16 + quad * 4 + reg;
                Opart[obase + (size_t)gr * DV + dt * 16 + n] = f2bf(Oacc[qt][dt][reg]);
            }
#pragma unroll
    for (int qt = 0; qt < 2; ++qt) {
        float r = lrow[qt];
        r += __shfl_xor(r, 16);
        r += __shfl_xor(r, 32);
        if (quad == 0)
            Lpart[ly * N_Q + qrow0 + qt * 16 + n] = r;
    }
}

// ---------------------------------------------------------------------------
// Flash kernel: in-device mask-dtype detection (element count can't
// distinguish 1B vs 4B storage host-side), then dispatch to matching body.
// Both bodies share the kernel-scope LDS (64 KB -> 2 blocks/CU).
// ---------------------------------------------------------------------------
__global__ __launch_bounds__(256, 2) void flash_kernel(
    const unsigned short* __restrict__ Qw, const unsigned short* __restrict__ Kw,
    const unsigned short* __restrict__ Vt, const unsigned int* __restrict__ mask,
    unsigned short* __restrict__ Opart, float* __restrict__ Lpart,
    int nsplit, int lgNs)
{
    __shared__ __align__(16) unsigned short k_lds[2][64 * 128];  // 2 x 16 KB
    __shared__ __align__(16) unsigned short vt_lds[256 * 64];    // 32 KB

    // dtype detect on first 64 words (L2-hot; identical across waves/blocks):
    // f32 1.0 pattern -> 4-byte; word>1 -> packed uint8; else int32 -> 4-byte
    unsigned w0 = mask[threadIdx.x & 63];
    bool isf = (w0 == 0x3f800000u);
    bool isb = (w0 > 1u) && !isf;
    bool wide = (__ballot(isf) != 0ull) || (__ballot(isb) == 0ull);

    if (wide)
        flash_body<4>(Qw, Kw, Vt, mask, Opart, Lpart, nsplit, lgNs,
                      &k_lds[0][0], vt_lds);
    else
        flash_body<1>(Qw, Kw, Vt, mask, Opart, Lpart, nsplit, lgNs,
                      &k_lds[0][0], vt_lds);
}

// ---------------------------------------------------------------------------
// Combine: out = (sum_c O_c) / (sum_c l_c).
// ---------------------------------------------------------------------------
__global__ __launch_bounds__(256) void combine_kernel(
    const unsigned short* __restrict__ Opart, const float* __restrict__ Lpart,
    float* __restrict__ out, int nsplit)
{
    const int row = blockIdx.x, d = threadIdx.x;
    float L = 0.f, o = 0.f;
    for (int c = 0; c < nsplit; ++c) {
        L += Lpart[c * N_Q + row];
        unsigned int b = Opart[((size_t)c * N_Q + row) * DV + d];
        o += __uint_as_float(b << 16);
    }
    out[(size_t)row * DV + d] = o / L;
}

// ---------------------------------------------------------------------------
extern "C" void kernel_launch(void* const* d_in, const int* in_sizes, int n_in,
                              void* d_out, int out_size, void* d_ws, size_t ws_size,
                              hipStream_t stream)
{
    const float* main_feat  = (const float*)d_in[0];
    const float* other_feat = (const float*)d_in[1];
    const float* fix_feat   = (const float*)d_in[2];
    const void*  mask       = d_in[3];
    const float* Wq         = (const float*)d_in[4];
    const float* bq         = (const float*)d_in[5];
    const float* Wk         = (const float*)d_in[6];
    const float* bk         = (const float*)d_in[7];
    float* out = (float*)d_out;

    char* ws = (char*)d_ws;
    unsigned short* Qw = (unsigned short*)(ws);                         // 2 MB
    unsigned short* Kw = (unsigned short*)(ws + (1ull << 21));          // 2 MB
    unsigned short* Vt = (unsigned short*)(ws + (2ull << 21));          // 4 MB
    float* Lpart = (float*)(ws + (16ull << 20) + 2048);

    const size_t base = (16ull << 20) + 2048;
    auto need = [&](int ns) {
        return base + (size_t)ns * N_Q * 4 + (size_t)ns * N_Q * DV * 2;
    };
    int nsplit = 1, lgNs = 0;
    if (ws_size >= need(8))      { nsplit = 8; lgNs = 3; }
    else if (ws_size >= need(4)) { nsplit = 4; lgNs = 2; }
    else if (ws_size >= need(2)) { nsplit = 2; lgNs = 1; }

    unsigned short* Opart = (unsigned short*)(Lpart + (size_t)nsplit * N_Q);

    hipLaunchKernelGGL(proj_kernel, dim3(128, 2), dim3(256), 0, stream,
                       main_feat, Wq, bq, other_feat, Wk, bk, Qw, Kw);
    hipLaunchKernelGGL(build_vt_kernel, dim3(128, 4), dim3(256), 0, stream,
                       other_feat, fix_feat, Vt);
    hipLaunchKernelGGL(flash_kernel, dim3(64, nsplit), dim3(256), 0, stream,
                       Qw, Kw, Vt, (const unsigned int*)mask, Opart, Lpart, nsplit, lgNs);
    hipLaunchKernelGGL(combine_kernel, dim3(N_Q), dim3(256), 0, stream,
                       Opart, Lpart, out, nsplit);
}

// Round 6
// 519.858 us; speedup vs baseline: 1.2539x; 1.2539x over previous
//
#include <hip/hip_runtime.h>
#include <hip/hip_bf16.h>
#include <stdint.h>

typedef __attribute__((ext_vector_type(8))) short short8;
typedef __attribute__((ext_vector_type(4))) float floatx4;

#define MFMA32K(a, b, c) __builtin_amdgcn_mfma_f32_16x16x32_bf16(a, b, c, 0, 0, 0)

constexpr int N_Q  = 8192;
constexpr int M_KV = 8192;
constexpr int DMID = 128;
constexpr int DV   = 256;

__device__ __forceinline__ unsigned short f2bf(float x) {
    unsigned u = __float_as_uint(x);
    u += 0x7fffu + ((u >> 16) & 1u);
    return (unsigned short)(u >> 16);
}

__device__ __forceinline__ short8 cvt_f8_bf8(float4 a, float4 b) {
    short8 r;
    r[0] = (short)f2bf(a.x); r[1] = (short)f2bf(a.y);
    r[2] = (short)f2bf(a.z); r[3] = (short)f2bf(a.w);
    r[4] = (short)f2bf(b.x); r[5] = (short)f2bf(b.y);
    r[6] = (short)f2bf(b.z); r[7] = (short)f2bf(b.w);
    return r;
}

// async global->LDS, 16B per lane; lds dst is wave-uniform (HW adds lane*16)
__device__ __forceinline__ void gl_lds16(const unsigned short* g, unsigned short* l) {
    __builtin_amdgcn_global_load_lds(
        (const __attribute__((address_space(1))) unsigned int*)g,
        (__attribute__((address_space(3))) unsigned int*)l, 16, 0, 0);
}

// nonzero-byte -> 4-bit mask (bit i = byte i != 0)
__device__ __forceinline__ unsigned nz4(unsigned x) {
    unsigned nz = (((x & 0x7f7f7f7fu) + 0x7f7f7f7fu) | x) & 0x80808080u;
    unsigned a = (nz >> 7) & 0x01010101u;
    return (a * 0x01020408u) >> 24;
}

// ---------------------------------------------------------------------------
// Projections: dst[row] = src[row] @ W^T + bias, bf16, 16B-unit rotation
// within the row: unit' = (unit + row) & 15.
// ---------------------------------------------------------------------------
__global__ __launch_bounds__(256) void proj_kernel(
    const float* __restrict__ main_feat, const float* __restrict__ Wq, const float* __restrict__ bq,
    const float* __restrict__ other_feat, const float* __restrict__ Wk, const float* __restrict__ bk,
    unsigned short* __restrict__ Qw, unsigned short* __restrict__ Kw)
{
    const float* src;  const float* W;  const float* bias;  unsigned short* dst;
    if (blockIdx.y == 0) { src = main_feat;  W = Wq; bias = bq; dst = Qw; }
    else                 { src = other_feat; W = Wk; bias = bk; dst = Kw; }

    const int wave = threadIdx.x >> 6, lane = threadIdx.x & 63;
    const int n = lane & 15, quad = lane >> 4;
    const int row0 = blockIdx.x * 64 + wave * 16;

    short8 a[8];
    const float* ap = src + (size_t)(row0 + n) * 256 + quad * 8;
#pragma unroll
    for (int ks = 0; ks < 8; ++ks) {
        float4 x0 = *(const float4*)(ap + ks * 32);
        float4 x1 = *(const float4*)(ap + ks * 32 + 4);
        a[ks] = cvt_f8_bf8(x0, x1);
    }

    floatx4 acc[8];
#pragma unroll
    for (int nt = 0; nt < 8; ++nt) acc[nt] = floatx4{0.f, 0.f, 0.f, 0.f};

#pragma unroll
    for (int nt = 0; nt < 8; ++nt) {
        const float* wp = W + (size_t)(nt * 16 + n) * 256 + quad * 8;
#pragma unroll
        for (int ks = 0; ks < 8; ++ks) {
            float4 w0 = *(const float4*)(wp + ks * 32);
            float4 w1 = *(const float4*)(wp + ks * 32 + 4);
            short8 b = cvt_f8_bf8(w0, w1);
            acc[nt] = MFMA32K(a[ks], b, acc[nt]);
        }
    }

#pragma unroll
    for (int nt = 0; nt < 8; ++nt) {
        float bb = bias[nt * 16 + n];
#pragma unroll
        for (int reg = 0; reg < 4; ++reg) {
            int r = row0 + quad * 4 + reg;
            int c = nt * 16 + n;
            int phys = ((((c >> 3) + r) & 15) << 3) | (c & 7);
            dst[(size_t)r * DMID + phys] = f2bf(acc[nt][reg] + bb);
        }
    }
}

// ---------------------------------------------------------------------------
// Vt[d][col(m)] = fix[m] * other[m][d]; col = pc-permutation (kv=32e+16s+4q+j
// -> pc=32e+8q+4s+j) composed with 16B-unit rotation by d per 64-col group.
// ---------------------------------------------------------------------------
__global__ __launch_bounds__(256) void build_vt_kernel(
    const float* __restrict__ other_feat, const float* __restrict__ fix_feat,
    unsigned short* __restrict__ Vt)
{
    __shared__ unsigned short tile[64 * 72];
    const int t = threadIdx.x;
    const int m0 = blockIdx.x * 64, d0 = blockIdx.y * 64;

#pragma unroll
    for (int r = 0; r < 4; ++r) {
        int idx = r * 256 + t;
        int ml = idx >> 4, dl4 = (idx & 15) * 4;
        float4 v = *(const float4*)(other_feat + (size_t)(m0 + ml) * 256 + d0 + dl4);
        float f = fix_feat[m0 + ml];
        tile[(dl4 + 0) * 72 + ml] = f2bf(v.x * f);
        tile[(dl4 + 1) * 72 + ml] = f2bf(v.y * f);
        tile[(dl4 + 2) * 72 + ml] = f2bf(v.z * f);
        tile[(dl4 + 3) * 72 + ml] = f2bf(v.w * f);
    }
    __syncthreads();
#pragma unroll
    for (int r = 0; r < 8; ++r) {
        int dl = r * 8 + (t >> 5);
        int d = d0 + dl;
        int ml = (t & 31) * 2;
        int e = ml >> 5, s = (ml >> 4) & 1, q = (ml >> 2) & 3, j = ml & 3;
        int pc = e * 32 + q * 8 + s * 4 + j;
        int phys = ((((pc >> 3) + d) & 7) << 3) | (pc & 7);
        unsigned int v0 = tile[dl * 72 + ml];
        unsigned int v1 = tile[dl * 72 + ml + 1];
        *(unsigned int*)(Vt + (size_t)d * M_KV + m0 + phys) = v0 | (v1 << 16);
    }
}

// ---------------------------------------------------------------------------
// Flash attention body — R4 structure (global_load_lds DMA for K/Vt, mask in
// regs; VGPR~128, no spill) with COUNTED-vmcnt barriers so the HBM mask
// stream stays in flight across the whole iteration:
//   per-iter issue order: Vt(it) DMA [8] ; K(it+1) DMA [4] ; mask(it+1) [8]
//   alpha barrier: lgkmcnt(0) only (K(it) was drained at prev beta)
//   beta barrier:  vmcnt(8) -> drains Vt+K (12 oldest), masks keep flying
//                  (vmcnt(0) on last iter where no K/mask were issued)
//   compress(it+1) AFTER PV (sched_barrier-pinned) -> mask cover =
//   QK+softmax+beta+PV instead of PV-only.
// ESZ = mask element size (4: int32/f32 nonzero; 1: bool/uint8), chosen by
// in-device dtype detection in the caller.
// BM=128, K double-buffered, Vt single-buffered, S^T formulation,
// all-16x16x32 MFMA, pc-permuted Vt, no online max. LDS 64 KB -> 2 blk/CU.
// ---------------------------------------------------------------------------
template<int ESZ>
__device__ __forceinline__ void flash_body(
    const unsigned short* __restrict__ Qw, const unsigned short* __restrict__ Kw,
    const unsigned short* __restrict__ Vt, const unsigned int* __restrict__ mask,
    unsigned short* __restrict__ Opart, float* __restrict__ Lpart,
    int nsplit, int lgNs,
    unsigned short* k_lds /* 2 x 64 x 128 */, unsigned short* vt_lds /* 256 x 64 */)
{
    const int L = blockIdx.x + gridDim.x * blockIdx.y;
    const int ly = L & (nsplit - 1);      // L&7 == XCD id under round-robin
    const int lx = L >> lgNs;             // -> per-XCD L2-resident K/V chunk
    const int chunkLen = M_KV >> lgNs;
    const int mBeg = ly * chunkLen;
    const int tid = threadIdx.x;
    const int wave = tid >> 6, lane = tid & 63, n = lane & 15, quad = lane >> 4;
    const int qrow0 = lx * 128 + wave * 32;
    constexpr float SC = 0.08838834764831845f * 1.4426950408889634f; // scale*log2(e)

    // Q fragments (rotated layout: unit' = (unit + row) & 15)
    short8 qf[2][4];
#pragma unroll
    for (int qt = 0; qt < 2; ++qt)
#pragma unroll
        for (int db = 0; db < 4; ++db) {
            int row = qrow0 + qt * 16 + n;
            int phys = (db * 4 + quad + row) & 15;
            qf[qt][db] = *(const short8*)(Qw + (size_t)row * DMID + phys * 8);
        }

    floatx4 Oacc[2][16];
#pragma unroll
    for (int qt = 0; qt < 2; ++qt)
#pragma unroll
        for (int dt = 0; dt < 16; ++dt) Oacc[qt][dt] = floatx4{0.f, 0.f, 0.f, 0.f};

    float lrow[2] = {0.f, 0.f};

    // staging invariants
    const unsigned short* kg = Kw + (size_t)(wave * 4 + (lane >> 4)) * DMID + (lane & 15) * 8;
    const unsigned short* vg = Vt + (size_t)(wave * 8 + (lane >> 3)) * M_KV + (lane & 7) * 8;
    unsigned short* vld = &vt_lds[wave * 512];
    const int kqn = quad + n;

    // raw-mask prefetch registers + current/next predicate words
    uint4    mv4[2][4];   // ESZ==4: 16 elems/lane (cols m0+kvt*16+quad*4+j)
    unsigned mv1[2][4];   // ESZ==1: same cols, 4 bytes per dword
    unsigned wq[2];       // predicates for the CURRENT iteration

    auto load_mask = [&](int m0l) {
#pragma unroll
        for (int qt = 0; qt < 2; ++qt) {
            const size_t row = (size_t)(qrow0 + qt * 16 + n);
            if constexpr (ESZ == 4) {
                const unsigned* mp = mask + row * M_KV + m0l + quad * 4;
#pragma unroll
                for (int kvt = 0; kvt < 4; ++kvt)
                    mv4[qt][kvt] = *(const uint4*)(mp + kvt * 16);
            } else {
                const unsigned* mp = mask + row * (M_KV / 4) + (m0l >> 2) + quad;
#pragma unroll
                for (int kvt = 0; kvt < 4; ++kvt)
                    mv1[qt][kvt] = mp[kvt * 4];
            }
        }
    };
    auto compress = [&]() {
#pragma unroll
        for (int qt = 0; qt < 2; ++qt) {
            unsigned b = 0;
            if constexpr (ESZ == 4) {
#pragma unroll
                for (int kvt = 0; kvt < 4; ++kvt) {
                    const unsigned* c = (const unsigned*)&mv4[qt][kvt];
#pragma unroll
                    for (int j = 0; j < 4; ++j)
                        b |= (c[j] != 0u ? 1u : 0u) << (kvt * 4 + j);
                }
            } else {
#pragma unroll
                for (int kvt = 0; kvt < 4; ++kvt)
                    b |= nz4(mv1[qt][kvt]) << (kvt * 4);
            }
            wq[qt] = b;
        }
    };

    const int iters = chunkLen / 64;

    // prologue: K(0) DMA, mask(0) load+compress, drain K(0)
#pragma unroll
    for (int r = 0; r < 4; ++r)
        gl_lds16(kg + (size_t)(mBeg + r * 16) * DMID, &k_lds[wave * 512 + r * 2048]);
    load_mask(mBeg);
    compress();                                  // waits masks (compiler vmcnt)
    asm volatile("s_waitcnt vmcnt(0)" ::: "memory");   // K(0) in LDS

    for (int it = 0; it < iters; ++it) {
        const int m0 = mBeg + it * 64;
        const unsigned short* kbuf = k_lds + (it & 1) * 8192;

        // alpha: K(it) already drained at prev beta; only ds ops to settle
        asm volatile("s_waitcnt lgkmcnt(0)\n\ts_barrier" ::: "memory");

        // ---- issue phase (order defines vmcnt ages: Vt oldest, masks newest)
#pragma unroll
        for (int r = 0; r < 8; ++r)                       // Vt(it) [8]
            gl_lds16(vg + (size_t)(r * 32) * M_KV + m0, vld + r * 2048);
        if (it + 1 < iters) {
            unsigned short* knext = k_lds + ((it + 1) & 1) * 8192 + wave * 512;
#pragma unroll
            for (int r = 0; r < 4; ++r)                   // K(it+1) [4]
                gl_lds16(kg + (size_t)(m0 + 64 + r * 16) * DMID, knext + r * 2048);
            load_mask(m0 + 64);                           // mask(it+1) [8]
        }
        __builtin_amdgcn_sched_barrier(0);   // pin issues before QK

        // ---- S^T = K Q^T (kv = 16kvt + 4quad + reg, q = n) ----
        floatx4 ST[4][2];
        __builtin_amdgcn_s_setprio(1);
#pragma unroll
        for (int kvt = 0; kvt < 4; ++kvt) {
            const int rowoff = (kvt * 16 + n) * DMID;
            short8 a0 = *(const short8*)&kbuf[rowoff + (((kqn + 0) & 15) << 3)];
            short8 a1 = *(const short8*)&kbuf[rowoff + (((kqn + 4) & 15) << 3)];
            short8 a2 = *(const short8*)&kbuf[rowoff + (((kqn + 8) & 15) << 3)];
            short8 a3 = *(const short8*)&kbuf[rowoff + (((kqn + 12) & 15) << 3)];
#pragma unroll
            for (int qt = 0; qt < 2; ++qt) {
                floatx4 s = floatx4{0.f, 0.f, 0.f, 0.f};
                s = MFMA32K(a0, qf[qt][0], s);
                s = MFMA32K(a1, qf[qt][1], s);
                s = MFMA32K(a2, qf[qt][2], s);
                s = MFMA32K(a3, qf[qt][3], s);
                ST[kvt][qt] = s;
            }
        }
        __builtin_amdgcn_s_setprio(0);

        // ---- p = exp2(s*SC), 0 where masked (wq from PREV iter's compress)
        short8 pf8[2][2];
#pragma unroll
        for (int qt = 0; qt < 2; ++qt) {
            const unsigned x = wq[qt];
            float lacc = 0.f;
#pragma unroll
            for (int kvt = 0; kvt < 4; ++kvt) {
                int e = kvt >> 1, s = kvt & 1;
                float p[4];
#pragma unroll
                for (int j = 0; j < 4; ++j) {
                    float v = __builtin_amdgcn_exp2f(ST[kvt][qt][j] * SC);
                    p[j] = ((x >> (kvt * 4 + j)) & 1u) ? 0.f : v;
                    lacc += p[j];
                }
                __hip_bfloat162 h0 = __float22bfloat162_rn(make_float2(p[0], p[1]));
                __hip_bfloat162 h1 = __float22bfloat162_rn(make_float2(p[2], p[3]));
                unsigned u0, u1;
                __builtin_memcpy(&u0, &h0, 4);
                __builtin_memcpy(&u1, &h1, 4);
                ((unsigned*)&pf8[qt][e])[s * 2 + 0] = u0;
                ((unsigned*)&pf8[qt][e])[s * 2 + 1] = u1;
            }
            lrow[qt] += lacc;
        }

        // beta: drain Vt(it)+K(it+1) (12 oldest), leave mask(it+1) in flight
        if (it + 1 < iters)
            asm volatile("s_waitcnt vmcnt(8) lgkmcnt(0)\n\ts_barrier" ::: "memory");
        else
            asm volatile("s_waitcnt vmcnt(0) lgkmcnt(0)\n\ts_barrier" ::: "memory");

        // ---- O += P V (rotated contiguous b128 from vt_lds) ----
        __builtin_amdgcn_s_setprio(1);
#pragma unroll
        for (int e = 0; e < 2; ++e) {
#pragma unroll
            for (int dt = 0; dt < 16; ++dt) {
                const int vb = (dt * 16 + n) * 64 + (((e * 4 + quad + n) & 7) << 3);
                short8 bv = *(const short8*)&vt_lds[vb];
                Oacc[0][dt] = MFMA32K(pf8[0][e], bv, Oacc[0][dt]);
                Oacc[1][dt] = MFMA32K(pf8[1][e], bv, Oacc[1][dt]);
            }
        }
        __builtin_amdgcn_s_setprio(0);

        // compress(it+1) AFTER PV: masks were in flight QK+SM+beta+PV
        __builtin_amdgcn_sched_barrier(0);   // keep compress (and its wait) here
        if (it + 1 < iters) compress();
    }

    // ---- epilogue: bf16 partials + cross-quad l reduction ----
    const size_t obase = (size_t)ly * N_Q * DV;
#pragma unroll
    for (int qt = 0; qt < 2; ++qt)
#pragma unroll
        for (int dt = 0; dt < 16; ++dt)
#pragma unroll
            for (int reg = 0; reg < 4; ++reg) {
                int gr = qrow0 + qt * 16 + quad * 4 + reg;
                Opart[obase + (size_t)gr * DV + dt * 16 + n] = f2bf(Oacc[qt][dt][reg]);
            }
#pragma unroll
    for (int qt = 0; qt < 2; ++qt) {
        float r = lrow[qt];
        r += __shfl_xor(r, 16);
        r += __shfl_xor(r, 32);
        if (quad == 0)
            Lpart[ly * N_Q + qrow0 + qt * 16 + n] = r;
    }
}

// ---------------------------------------------------------------------------
// Flash kernel: in-device mask-dtype detection (element count can't
// distinguish 1B vs 4B storage host-side), then dispatch to matching body.
// Both bodies share the kernel-scope LDS (64 KB -> 2 blocks/CU).
// ---------------------------------------------------------------------------
__global__ __launch_bounds__(256, 2) void flash_kernel(
    const unsigned short* __restrict__ Qw, const unsigned short* __restrict__ Kw,
    const unsigned short* __restrict__ Vt, const unsigned int* __restrict__ mask,
    unsigned short* __restrict__ Opart, float* __restrict__ Lpart,
    int nsplit, int lgNs)
{
    __shared__ __align__(16) unsigned short k_lds[2][64 * 128];  // 2 x 16 KB
    __shared__ __align__(16) unsigned short vt_lds[256 * 64];    // 32 KB

    // dtype detect on first 64 words (L2-hot; identical across waves/blocks):
    // f32 1.0 pattern -> 4-byte; word>1 -> packed uint8; else int32 -> 4-byte
    unsigned w0 = mask[threadIdx.x & 63];
    bool isf = (w0 == 0x3f800000u);
    bool isb = (w0 > 1u) && !isf;
    bool wide = (__ballot(isf) != 0ull) || (__ballot(isb) == 0ull);

    if (wide)
        flash_body<4>(Qw, Kw, Vt, mask, Opart, Lpart, nsplit, lgNs,
                      &k_lds[0][0], vt_lds);
    else
        flash_body<1>(Qw, Kw, Vt, mask, Opart, Lpart, nsplit, lgNs,
                      &k_lds[0][0], vt_lds);
}

// ---------------------------------------------------------------------------
// Combine: out = (sum_c O_c) / (sum_c l_c).
// ---------------------------------------------------------------------------
__global__ __launch_bounds__(256) void combine_kernel(
    const unsigned short* __restrict__ Opart, const float* __restrict__ Lpart,
    float* __restrict__ out, int nsplit)
{
    const int row = blockIdx.x, d = threadIdx.x;
    float L = 0.f, o = 0.f;
    for (int c = 0; c < nsplit; ++c) {
        L += Lpart[c * N_Q + row];
        unsigned int b = Opart[((size_t)c * N_Q + row) * DV + d];
        o += __uint_as_float(b << 16);
    }
    out[(size_t)row * DV + d] = o / L;
}

// ---------------------------------------------------------------------------
extern "C" void kernel_launch(void* const* d_in, const int* in_sizes, int n_in,
                              void* d_out, int out_size, void* d_ws, size_t ws_size,
                              hipStream_t stream)
{
    const float* main_feat  = (const float*)d_in[0];
    const float* other_feat = (const float*)d_in[1];
    const float* fix_feat   = (const float*)d_in[2];
    const void*  mask       = d_in[3];
    const float* Wq         = (const float*)d_in[4];
    const float* bq         = (const float*)d_in[5];
    const float* Wk         = (const float*)d_in[6];
    const float* bk         = (const float*)d_in[7];
    float* out = (float*)d_out;

    char* ws = (char*)d_ws;
    unsigned short* Qw = (unsigned short*)(ws);                         // 2 MB
    unsigned short* Kw = (unsigned short*)(ws + (1ull << 21));          // 2 MB
    unsigned short* Vt = (unsigned short*)(ws + (2ull << 21));          // 4 MB
    float* Lpart = (float*)(ws + (16ull << 20) + 2048);

    const size_t base = (16ull << 20) + 2048;
    auto need = [&](int ns) {
        return base + (size_t)ns * N_Q * 4 + (size_t)ns * N_Q * DV * 2;
    };
    int nsplit = 1, lgNs = 0;
    if (ws_size >= need(8))      { nsplit = 8; lgNs = 3; }
    else if (ws_size >= need(4)) { nsplit = 4; lgNs = 2; }
    else if (ws_size >= need(2)) { nsplit = 2; lgNs = 1; }

    unsigned short* Opart = (unsigned short*)(Lpart + (size_t)nsplit * N_Q);

    hipLaunchKernelGGL(proj_kernel, dim3(128, 2), dim3(256), 0, stream,
                       main_feat, Wq, bq, other_feat, Wk, bk, Qw, Kw);
    hipLaunchKernelGGL(build_vt_kernel, dim3(128, 4), dim3(256), 0, stream,
                       other_feat, fix_feat, Vt);
    hipLaunchKernelGGL(flash_kernel, dim3(64, nsplit), dim3(256), 0, stream,
                       Qw, Kw, Vt, (const unsigned int*)mask, Opart, Lpart, nsplit, lgNs);
    hipLaunchKernelGGL(combine_kernel, dim3(N_Q), dim3(256), 0, stream,
                       Opart, Lpart, out, nsplit);
}

// Round 7
// 489.804 us; speedup vs baseline: 1.3309x; 1.0614x over previous
//
#include <hip/hip_runtime.h>
#include <hip/hip_bf16.h>
#include <stdint.h>

typedef __attribute__((ext_vector_type(8))) short short8;
typedef __attribute__((ext_vector_type(4))) float floatx4;

#define MFMA32K(a, b, c) __builtin_amdgcn_mfma_f32_16x16x32_bf16(a, b, c, 0, 0, 0)

constexpr int N_Q  = 8192;
constexpr int M_KV = 8192;
constexpr int DMID = 128;
constexpr int DV   = 256;

__device__ __forceinline__ unsigned short f2bf(float x) {
    unsigned u = __float_as_uint(x);
    u += 0x7fffu + ((u >> 16) & 1u);
    return (unsigned short)(u >> 16);
}

__device__ __forceinline__ short8 cvt_f8_bf8(float4 a, float4 b) {
    short8 r;
    r[0] = (short)f2bf(a.x); r[1] = (short)f2bf(a.y);
    r[2] = (short)f2bf(a.z); r[3] = (short)f2bf(a.w);
    r[4] = (short)f2bf(b.x); r[5] = (short)f2bf(b.y);
    r[6] = (short)f2bf(b.z); r[7] = (short)f2bf(b.w);
    return r;
}

// async global->LDS, 16B per lane; lds dst is wave-uniform (HW adds lane*16)
__device__ __forceinline__ void gl_lds16(const unsigned short* g, unsigned short* l) {
    __builtin_amdgcn_global_load_lds(
        (const __attribute__((address_space(1))) unsigned int*)g,
        (__attribute__((address_space(3))) unsigned int*)l, 16, 0, 0);
}

// nonzero-byte -> 4-bit mask (bit i = byte i != 0)
__device__ __forceinline__ unsigned nz4(unsigned x) {
    unsigned nz = (((x & 0x7f7f7f7fu) + 0x7f7f7f7fu) | x) & 0x80808080u;
    unsigned a = (nz >> 7) & 0x01010101u;
    return (a * 0x01020408u) >> 24;
}

// ---------------------------------------------------------------------------
// Projections: dst[row] = src[row] @ W^T + bias, bf16, 16B-unit rotation
// within the row: unit' = (unit + row) & 15.
// ---------------------------------------------------------------------------
__global__ __launch_bounds__(256) void proj_kernel(
    const float* __restrict__ main_feat, const float* __restrict__ Wq, const float* __restrict__ bq,
    const float* __restrict__ other_feat, const float* __restrict__ Wk, const float* __restrict__ bk,
    unsigned short* __restrict__ Qw, unsigned short* __restrict__ Kw)
{
    const float* src;  const float* W;  const float* bias;  unsigned short* dst;
    if (blockIdx.y == 0) { src = main_feat;  W = Wq; bias = bq; dst = Qw; }
    else                 { src = other_feat; W = Wk; bias = bk; dst = Kw; }

    const int wave = threadIdx.x >> 6, lane = threadIdx.x & 63;
    const int n = lane & 15, quad = lane >> 4;
    const int row0 = blockIdx.x * 64 + wave * 16;

    short8 a[8];
    const float* ap = src + (size_t)(row0 + n) * 256 + quad * 8;
#pragma unroll
    for (int ks = 0; ks < 8; ++ks) {
        float4 x0 = *(const float4*)(ap + ks * 32);
        float4 x1 = *(const float4*)(ap + ks * 32 + 4);
        a[ks] = cvt_f8_bf8(x0, x1);
    }

    floatx4 acc[8];
#pragma unroll
    for (int nt = 0; nt < 8; ++nt) acc[nt] = floatx4{0.f, 0.f, 0.f, 0.f};

#pragma unroll
    for (int nt = 0; nt < 8; ++nt) {
        const float* wp = W + (size_t)(nt * 16 + n) * 256 + quad * 8;
#pragma unroll
        for (int ks = 0; ks < 8; ++ks) {
            float4 w0 = *(const float4*)(wp + ks * 32);
            float4 w1 = *(const float4*)(wp + ks * 32 + 4);
            short8 b = cvt_f8_bf8(w0, w1);
            acc[nt] = MFMA32K(a[ks], b, acc[nt]);
        }
    }

#pragma unroll
    for (int nt = 0; nt < 8; ++nt) {
        float bb = bias[nt * 16 + n];
#pragma unroll
        for (int reg = 0; reg < 4; ++reg) {
            int r = row0 + quad * 4 + reg;
            int c = nt * 16 + n;
            int phys = ((((c >> 3) + r) & 15) << 3) | (c & 7);
            dst[(size_t)r * DMID + phys] = f2bf(acc[nt][reg] + bb);
        }
    }
}

// ---------------------------------------------------------------------------
// Vt[d][col(m)] = fix[m] * other[m][d]; col = pc-permutation (kv=32e+16s+4q+j
// -> pc=32e+8q+4s+j) composed with 16B-unit rotation by d per 64-col group.
// ---------------------------------------------------------------------------
__global__ __launch_bounds__(256) void build_vt_kernel(
    const float* __restrict__ other_feat, const float* __restrict__ fix_feat,
    unsigned short* __restrict__ Vt)
{
    __shared__ unsigned short tile[64 * 72];
    const int t = threadIdx.x;
    const int m0 = blockIdx.x * 64, d0 = blockIdx.y * 64;

#pragma unroll
    for (int r = 0; r < 4; ++r) {
        int idx = r * 256 + t;
        int ml = idx >> 4, dl4 = (idx & 15) * 4;
        float4 v = *(const float4*)(other_feat + (size_t)(m0 + ml) * 256 + d0 + dl4);
        float f = fix_feat[m0 + ml];
        tile[(dl4 + 0) * 72 + ml] = f2bf(v.x * f);
        tile[(dl4 + 1) * 72 + ml] = f2bf(v.y * f);
        tile[(dl4 + 2) * 72 + ml] = f2bf(v.z * f);
        tile[(dl4 + 3) * 72 + ml] = f2bf(v.w * f);
    }
    __syncthreads();
#pragma unroll
    for (int r = 0; r < 8; ++r) {
        int dl = r * 8 + (t >> 5);
        int d = d0 + dl;
        int ml = (t & 31) * 2;
        int e = ml >> 5, s = (ml >> 4) & 1, q = (ml >> 2) & 3, j = ml & 3;
        int pc = e * 32 + q * 8 + s * 4 + j;
        int phys = ((((pc >> 3) + d) & 7) << 3) | (pc & 7);
        unsigned int v0 = tile[dl * 72 + ml];
        unsigned int v1 = tile[dl * 72 + ml + 1];
        *(unsigned int*)(Vt + (size_t)d * M_KV + m0 + phys) = v0 | (v1 << 16);
    }
}

// ---------------------------------------------------------------------------
// Flash attention body — R4 schedule/barriers/register-profile, with the
// mask stream re-laid-out for DRAM efficiency:
//   * raw mask tile (128 rows x 64 cols) loaded COALESCED: each thread reads
//     64 CONTIGUOUS bytes (16 cols of one row; a wave covers 16 rows x 256 B
//     contiguous) -- 4x the granule of the old per-consumer gather.
//   * each thread compresses its 16 cols to 16 bits and writes a u16 into a
//     2 KB double-buffered LDS bitmap [parity][128 rows x u64].
//   * next iteration each thread ds_reads its row word and extracts its
//     nibble pattern -> bit-identical predicates to R4.
//   Loads are issued after sync2 (live through PV only -- the register
//   placement R4 proved spill-free); compressed+written after PV; visible at
//   next sync1 (__syncthreads drains lgkm+vmcnt as in R4).
// ESZ = mask element size (4: int32/f32 nonzero; 1: bool/uint8).
// BM=128, K double-buffered, Vt single-buffered, S^T formulation,
// all-16x16x32 MFMA, pc-permuted Vt, no online max. LDS 66 KB -> 2 blk/CU.
// ---------------------------------------------------------------------------
template<int ESZ>
__device__ __forceinline__ void flash_body(
    const unsigned short* __restrict__ Qw, const unsigned short* __restrict__ Kw,
    const unsigned short* __restrict__ Vt, const unsigned int* __restrict__ mask,
    unsigned short* __restrict__ Opart, float* __restrict__ Lpart,
    int nsplit, int lgNs,
    unsigned short* k_lds /* 2 x 64 x 128 */, unsigned short* vt_lds /* 256 x 64 */,
    unsigned long long* bm /* [2][128] u64 bitmap */)
{
    const int L = blockIdx.x + gridDim.x * blockIdx.y;
    const int ly = L & (nsplit - 1);      // L&7 == XCD id under round-robin
    const int lx = L >> lgNs;             // -> per-XCD L2-resident K/V chunk
    const int chunkLen = M_KV >> lgNs;
    const int mBeg = ly * chunkLen;
    const int tid = threadIdx.x;
    const int wave = tid >> 6, lane = tid & 63, n = lane & 15, quad = lane >> 4;
    const int qblk0 = lx * 128;           // block's first q row
    const int qrow0 = qblk0 + wave * 32;
    constexpr float SC = 0.08838834764831845f * 1.4426950408889634f; // scale*log2(e)

    // Q fragments (rotated layout: unit' = (unit + row) & 15)
    short8 qf[2][4];
#pragma unroll
    for (int qt = 0; qt < 2; ++qt)
#pragma unroll
        for (int db = 0; db < 4; ++db) {
            int row = qrow0 + qt * 16 + n;
            int phys = (db * 4 + quad + row) & 15;
            qf[qt][db] = *(const short8*)(Qw + (size_t)row * DMID + phys * 8);
        }

    floatx4 Oacc[2][16];
#pragma unroll
    for (int qt = 0; qt < 2; ++qt)
#pragma unroll
        for (int dt = 0; dt < 16; ++dt) Oacc[qt][dt] = floatx4{0.f, 0.f, 0.f, 0.f};

    float lrow[2] = {0.f, 0.f};

    // staging invariants
    const unsigned short* kg = Kw + (size_t)(wave * 4 + (lane >> 4)) * DMID + (lane & 15) * 8;
    const unsigned short* vg = Vt + (size_t)(wave * 8 + (lane >> 3)) * M_KV + (lane & 7) * 8;
    unsigned short* vld = &vt_lds[wave * 512];
    const int kqn = quad + n;

    // ---- mask raw-load / compress / bitmap helpers ----
    // ESZ==4: thread covers row lr4 = (r2*256+tid)>>2, cols c16*16..+15 (64 B)
    const int lr4  = tid >> 2;            // + r2*64
    const int c16q = tid & 3;
    // ESZ==1: thread tid<128 covers full row tid (64 B)
    uint4 vA[4], vB[4];

    auto issue_raw = [&](int m0l, int r2, uint4* v) {
        if constexpr (ESZ == 4) {
            const uint4* p = (const uint4*)(mask + (size_t)(qblk0 + r2 * 64 + lr4) * M_KV
                                            + m0l + c16q * 16);
#pragma unroll
            for (int k = 0; k < 4; ++k) v[k] = p[k];
        } else {
            if (tid < 128) {
                const uint4* p = (const uint4*)((const unsigned char*)mask
                                 + (size_t)(qblk0 + tid) * M_KV + m0l);
#pragma unroll
                for (int k = 0; k < 4; ++k) v[k] = p[k];
            }
        }
    };
    auto compress_write = [&](int buf, int r2, const uint4* v) {
        if constexpr (ESZ == 4) {
            unsigned b = 0;
#pragma unroll
            for (int k = 0; k < 4; ++k) {
                b |= (v[k].x != 0u ? 1u : 0u) << (k * 4 + 0);
                b |= (v[k].y != 0u ? 1u : 0u) << (k * 4 + 1);
                b |= (v[k].z != 0u ? 1u : 0u) << (k * 4 + 2);
                b |= (v[k].w != 0u ? 1u : 0u) << (k * 4 + 3);
            }
            *(unsigned short*)((char*)bm + buf * 1024 + (r2 * 64 + lr4) * 8 + c16q * 2)
                = (unsigned short)b;
        } else {
            if (tid < 128) {
                unsigned lo = nz4(v[0].x) | (nz4(v[0].y) << 4) | (nz4(v[0].z) << 8) | (nz4(v[0].w) << 12)
                            | (nz4(v[1].x) << 16) | (nz4(v[1].y) << 20) | (nz4(v[1].z) << 24) | (nz4(v[1].w) << 28);
                unsigned hi = nz4(v[2].x) | (nz4(v[2].y) << 4) | (nz4(v[2].z) << 8) | (nz4(v[2].w) << 12)
                            | (nz4(v[3].x) << 16) | (nz4(v[3].y) << 20) | (nz4(v[3].z) << 24) | (nz4(v[3].w) << 28);
                bm[buf * 128 + tid] = ((unsigned long long)hi << 32) | lo;
            }
        }
    };
    unsigned wq[2];
    auto read_wq = [&](int buf) {
        const unsigned q4 = quad * 4;
#pragma unroll
        for (int qt = 0; qt < 2; ++qt) {
            int lr = wave * 32 + qt * 16 + n;
            uint2 w = *(const uint2*)((const char*)bm + buf * 1024 + lr * 8);
            wq[qt] = ((w.x >> q4) & 0xFu) | (((w.x >> (16 + q4)) & 0xFu) << 4)
                   | (((w.y >> q4) & 0xFu) << 8) | (((w.y >> (16 + q4)) & 0xFu) << 12);
        }
    };

    const int iters = chunkLen / 64;

    // prologue: K(0) DMA; bitmap(0) built into parity buffer 0
#pragma unroll
    for (int r = 0; r < 4; ++r)
        gl_lds16(kg + (size_t)(mBeg + r * 16) * DMID, &k_lds[wave * 512 + r * 2048]);
    issue_raw(mBeg, 0, vA);
    if constexpr (ESZ == 4) issue_raw(mBeg, 1, vB);
    compress_write(0, 0, vA);
    if constexpr (ESZ == 4) compress_write(0, 1, vB);

    for (int it = 0; it < iters; ++it) {
        const int m0 = mBeg + it * 64;
        const unsigned short* kbuf = k_lds + (it & 1) * 8192;
        const int buf = it & 1, nbuf = buf ^ 1;

        __syncthreads();   // K(it) DMA drained; bitmap(it) writes visible

        // Vt(it) DMA (drained at mid barrier; overlaps QK+softmax)
#pragma unroll
        for (int r = 0; r < 8; ++r)
            gl_lds16(vg + (size_t)(r * 32) * M_KV + m0, vld + r * 2048);

        // predicates for this iteration from the LDS bitmap
        read_wq(buf);

        // ---- S^T = K Q^T (kv = 16kvt + 4quad + reg, q = n) ----
        floatx4 ST[4][2];
        __builtin_amdgcn_s_setprio(1);
#pragma unroll
        for (int kvt = 0; kvt < 4; ++kvt) {
            const int rowoff = (kvt * 16 + n) * DMID;
            short8 a0 = *(const short8*)&kbuf[rowoff + (((kqn + 0) & 15) << 3)];
            short8 a1 = *(const short8*)&kbuf[rowoff + (((kqn + 4) & 15) << 3)];
            short8 a2 = *(const short8*)&kbuf[rowoff + (((kqn + 8) & 15) << 3)];
            short8 a3 = *(const short8*)&kbuf[rowoff + (((kqn + 12) & 15) << 3)];
#pragma unroll
            for (int qt = 0; qt < 2; ++qt) {
                floatx4 s = floatx4{0.f, 0.f, 0.f, 0.f};
                s = MFMA32K(a0, qf[qt][0], s);
                s = MFMA32K(a1, qf[qt][1], s);
                s = MFMA32K(a2, qf[qt][2], s);
                s = MFMA32K(a3, qf[qt][3], s);
                ST[kvt][qt] = s;
            }
        }
        __builtin_amdgcn_s_setprio(0);

        // ---- p = exp2(s*SC), 0 where masked; pack to A-frags ----
        short8 pf8[2][2];
#pragma unroll
        for (int qt = 0; qt < 2; ++qt) {
            const unsigned x = wq[qt];
            float lacc = 0.f;
#pragma unroll
            for (int kvt = 0; kvt < 4; ++kvt) {
                int e = kvt >> 1, s = kvt & 1;
                float p[4];
#pragma unroll
                for (int j = 0; j < 4; ++j) {
                    float v = __builtin_amdgcn_exp2f(ST[kvt][qt][j] * SC);
                    p[j] = ((x >> (kvt * 4 + j)) & 1u) ? 0.f : v;
                    lacc += p[j];
                }
                __hip_bfloat162 h0 = __float22bfloat162_rn(make_float2(p[0], p[1]));
                __hip_bfloat162 h1 = __float22bfloat162_rn(make_float2(p[2], p[3]));
                unsigned u0, u1;
                __builtin_memcpy(&u0, &h0, 4);
                __builtin_memcpy(&u1, &h1, 4);
                ((unsigned*)&pf8[qt][e])[s * 2 + 0] = u0;
                ((unsigned*)&pf8[qt][e])[s * 2 + 1] = u1;
            }
            lrow[qt] += lacc;
        }

        __syncthreads();   // Vt(it) drained; QK reads done before K(it+1) writes

        // K(it+1) DMA + raw mask(it+1) loads (coalesced 64 B/lane; live
        // through PV only -- R4's proven spill-free placement)
        if (it + 1 < iters) {
            unsigned short* knext = k_lds + ((it + 1) & 1) * 8192 + wave * 512;
#pragma unroll
            for (int r = 0; r < 4; ++r)
                gl_lds16(kg + (size_t)(m0 + 64 + r * 16) * DMID, knext + r * 2048);
            issue_raw(m0 + 64, 0, vA);
            if constexpr (ESZ == 4) issue_raw(m0 + 64, 1, vB);
        }

        // ---- O += P V (rotated contiguous b128 from vt_lds) ----
        __builtin_amdgcn_s_setprio(1);
#pragma unroll
        for (int e = 0; e < 2; ++e) {
#pragma unroll
            for (int dt = 0; dt < 16; ++dt) {
                const int vb = (dt * 16 + n) * 64 + (((e * 4 + quad + n) & 7) << 3);
                short8 bv = *(const short8*)&vt_lds[vb];
                Oacc[0][dt] = MFMA32K(pf8[0][e], bv, Oacc[0][dt]);
                Oacc[1][dt] = MFMA32K(pf8[1][e], bv, Oacc[1][dt]);
            }
        }
        __builtin_amdgcn_s_setprio(0);

        // compress + bitmap(it+1) write (visible at next sync1)
        if (it + 1 < iters) {
            compress_write(nbuf, 0, vA);
            if constexpr (ESZ == 4) compress_write(nbuf, 1, vB);
        }
    }

    // ---- epilogue: bf16 partials + cross-quad l reduction ----
    const size_t obase = (size_t)ly * N_Q * DV;
#pragma unroll
    for (int qt = 0; qt < 2; ++qt)
#pragma unroll
        for (int dt = 0; dt < 16; ++dt)
#pragma unroll
            for (int reg = 0; reg < 4; ++reg) {
                int gr = qrow0 + qt * 16 + quad * 4 + reg;
                Opart[obase + (size_t)gr * DV + dt * 16 + n] = f2bf(Oacc[qt][dt][reg]);
            }
#pragma unroll
    for (int qt = 0; qt < 2; ++qt) {
        float r = lrow[qt];
        r += __shfl_xor(r, 16);
        r += __shfl_xor(r, 32);
        if (quad == 0)
            Lpart[ly * N_Q + qrow0 + qt * 16 + n] = r;
    }
}

// ---------------------------------------------------------------------------
// Flash kernel: in-device mask-dtype detection (element count can't
// distinguish 1B vs 4B storage host-side), then dispatch to matching body.
// Bodies share the kernel-scope LDS (66 KB -> 2 blocks/CU).
// ---------------------------------------------------------------------------
__global__ __launch_bounds__(256, 2) void flash_kernel(
    const unsigned short* __restrict__ Qw, const unsigned short* __restrict__ Kw,
    const unsigned short* __restrict__ Vt, const unsigned int* __restrict__ mask,
    unsigned short* __restrict__ Opart, float* __restrict__ Lpart,
    int nsplit, int lgNs)
{
    __shared__ __align__(16) unsigned short k_lds[2][64 * 128];  // 2 x 16 KB
    __shared__ __align__(16) unsigned short vt_lds[256 * 64];    // 32 KB
    __shared__ __align__(16) unsigned long long bitmap[2][128];  // 2 KB

    // dtype detect on first 64 words (L2-hot; identical across waves/blocks):
    // f32 1.0 pattern -> 4-byte; word>1 -> packed uint8; else int32 -> 4-byte
    unsigned w0 = mask[threadIdx.x & 63];
    bool isf = (w0 == 0x3f800000u);
    bool isb = (w0 > 1u) && !isf;
    bool wide = (__ballot(isf) != 0ull) || (__ballot(isb) == 0ull);

    if (wide)
        flash_body<4>(Qw, Kw, Vt, mask, Opart, Lpart, nsplit, lgNs,
                      &k_lds[0][0], vt_lds, &bitmap[0][0]);
    else
        flash_body<1>(Qw, Kw, Vt, mask, Opart, Lpart, nsplit, lgNs,
                      &k_lds[0][0], vt_lds, &bitmap[0][0]);
}

// ---------------------------------------------------------------------------
// Combine: out = (sum_c O_c) / (sum_c l_c).
// ---------------------------------------------------------------------------
__global__ __launch_bounds__(256) void combine_kernel(
    const unsigned short* __restrict__ Opart, const float* __restrict__ Lpart,
    float* __restrict__ out, int nsplit)
{
    const int row = blockIdx.x, d = threadIdx.x;
    float L = 0.f, o = 0.f;
    for (int c = 0; c < nsplit; ++c) {
        L += Lpart[c * N_Q + row];
        unsigned int b = Opart[((size_t)c * N_Q + row) * DV + d];
        o += __uint_as_float(b << 16);
    }
    out[(size_t)row * DV + d] = o / L;
}

// ---------------------------------------------------------------------------
extern "C" void kernel_launch(void* const* d_in, const int* in_sizes, int n_in,
                              void* d_out, int out_size, void* d_ws, size_t ws_size,
                              hipStream_t stream)
{
    const float* main_feat  = (const float*)d_in[0];
    const float* other_feat = (const float*)d_in[1];
    const float* fix_feat   = (const float*)d_in[2];
    const void*  mask       = d_in[3];
    const float* Wq         = (const float*)d_in[4];
    const float* bq         = (const float*)d_in[5];
    const float* Wk         = (const float*)d_in[6];
    const float* bk         = (const float*)d_in[7];
    float* out = (float*)d_out;

    char* ws = (char*)d_ws;
    unsigned short* Qw = (unsigned short*)(ws);                         // 2 MB
    unsigned short* Kw = (unsigned short*)(ws + (1ull << 21));          // 2 MB
    unsigned short* Vt = (unsigned short*)(ws + (2ull << 21));          // 4 MB
    float* Lpart = (float*)(ws + (16ull << 20) + 2048);

    const size_t base = (16ull << 20) + 2048;
    auto need = [&](int ns) {
        return base + (size_t)ns * N_Q * 4 + (size_t)ns * N_Q * DV * 2;
    };
    int nsplit = 1, lgNs = 0;
    if (ws_size >= need(8))      { nsplit = 8; lgNs = 3; }
    else if (ws_size >= need(4)) { nsplit = 4; lgNs = 2; }
    else if (ws_size >= need(2)) { nsplit = 2; lgNs = 1; }

    unsigned short* Opart = (unsigned short*)(Lpart + (size_t)nsplit * N_Q);

    hipLaunchKernelGGL(proj_kernel, dim3(128, 2), dim3(256), 0, stream,
                       main_feat, Wq, bq, other_feat, Wk, bk, Qw, Kw);
    hipLaunchKernelGGL(build_vt_kernel, dim3(128, 4), dim3(256), 0, stream,
                       other_feat, fix_feat, Vt);
    hipLaunchKernelGGL(flash_kernel, dim3(64, nsplit), dim3(256), 0, stream,
                       Qw, Kw, Vt, (const unsigned int*)mask, Opart, Lpart, nsplit, lgNs);
    hipLaunchKernelGGL(combine_kernel, dim3(N_Q), dim3(256), 0, stream,
                       Opart, Lpart, out, nsplit);
}

// Round 8
// 459.859 us; speedup vs baseline: 1.4175x; 1.0651x over previous
//
#include <hip/hip_runtime.h>
#include <hip/hip_bf16.h>
#include <stdint.h>

typedef __attribute__((ext_vector_type(8))) short short8;
typedef __attribute__((ext_vector_type(4))) float floatx4;

#define MFMA32K(a, b, c) __builtin_amdgcn_mfma_f32_16x16x32_bf16(a, b, c, 0, 0, 0)

constexpr int N_Q  = 8192;
constexpr int M_KV = 8192;
constexpr int DMID = 128;
constexpr int DV   = 256;

__device__ __forceinline__ unsigned short f2bf(float x) {
    unsigned u = __float_as_uint(x);
    u += 0x7fffu + ((u >> 16) & 1u);
    return (unsigned short)(u >> 16);
}

__device__ __forceinline__ short8 cvt_f8_bf8(float4 a, float4 b) {
    short8 r;
    r[0] = (short)f2bf(a.x); r[1] = (short)f2bf(a.y);
    r[2] = (short)f2bf(a.z); r[3] = (short)f2bf(a.w);
    r[4] = (short)f2bf(b.x); r[5] = (short)f2bf(b.y);
    r[6] = (short)f2bf(b.z); r[7] = (short)f2bf(b.w);
    return r;
}

// async global->LDS, 16B per lane; lds dst is wave-uniform (HW adds lane*16)
__device__ __forceinline__ void gl_lds16(const unsigned short* g, unsigned short* l) {
    __builtin_amdgcn_global_load_lds(
        (const __attribute__((address_space(1))) unsigned int*)g,
        (__attribute__((address_space(3))) unsigned int*)l, 16, 0, 0);
}

// nonzero-byte -> 4-bit mask (bit i = byte i != 0)
__device__ __forceinline__ unsigned nz4(unsigned x) {
    unsigned nz = (((x & 0x7f7f7f7fu) + 0x7f7f7f7fu) | x) & 0x80808080u;
    unsigned a = (nz >> 7) & 0x01010101u;
    return (a * 0x01020408u) >> 24;
}

// ---------------------------------------------------------------------------
// Projections: dst[row] = src[row] @ W^T + bias, bf16, 16B-unit rotation
// within the row: unit' = (unit + row) & 15.
// ---------------------------------------------------------------------------
__global__ __launch_bounds__(256) void proj_kernel(
    const float* __restrict__ main_feat, const float* __restrict__ Wq, const float* __restrict__ bq,
    const float* __restrict__ other_feat, const float* __restrict__ Wk, const float* __restrict__ bk,
    unsigned short* __restrict__ Qw, unsigned short* __restrict__ Kw)
{
    const float* src;  const float* W;  const float* bias;  unsigned short* dst;
    if (blockIdx.y == 0) { src = main_feat;  W = Wq; bias = bq; dst = Qw; }
    else                 { src = other_feat; W = Wk; bias = bk; dst = Kw; }

    const int wave = threadIdx.x >> 6, lane = threadIdx.x & 63;
    const int n = lane & 15, quad = lane >> 4;
    const int row0 = blockIdx.x * 64 + wave * 16;

    short8 a[8];
    const float* ap = src + (size_t)(row0 + n) * 256 + quad * 8;
#pragma unroll
    for (int ks = 0; ks < 8; ++ks) {
        float4 x0 = *(const float4*)(ap + ks * 32);
        float4 x1 = *(const float4*)(ap + ks * 32 + 4);
        a[ks] = cvt_f8_bf8(x0, x1);
    }

    floatx4 acc[8];
#pragma unroll
    for (int nt = 0; nt < 8; ++nt) acc[nt] = floatx4{0.f, 0.f, 0.f, 0.f};

#pragma unroll
    for (int nt = 0; nt < 8; ++nt) {
        const float* wp = W + (size_t)(nt * 16 + n) * 256 + quad * 8;
#pragma unroll
        for (int ks = 0; ks < 8; ++ks) {
            float4 w0 = *(const float4*)(wp + ks * 32);
            float4 w1 = *(const float4*)(wp + ks * 32 + 4);
            short8 b = cvt_f8_bf8(w0, w1);
            acc[nt] = MFMA32K(a[ks], b, acc[nt]);
        }
    }

#pragma unroll
    for (int nt = 0; nt < 8; ++nt) {
        float bb = bias[nt * 16 + n];
#pragma unroll
        for (int reg = 0; reg < 4; ++reg) {
            int r = row0 + quad * 4 + reg;
            int c = nt * 16 + n;
            int phys = ((((c >> 3) + r) & 15) << 3) | (c & 7);
            dst[(size_t)r * DMID + phys] = f2bf(acc[nt][reg] + bb);
        }
    }
}

// ---------------------------------------------------------------------------
// Vt[d][col(m)] = fix[m] * other[m][d]; col = pc-permutation (kv=32e+16s+4q+j
// -> pc=32e+8q+4s+j) composed with 16B-unit rotation by d per 64-col group.
// ---------------------------------------------------------------------------
__global__ __launch_bounds__(256) void build_vt_kernel(
    const float* __restrict__ other_feat, const float* __restrict__ fix_feat,
    unsigned short* __restrict__ Vt)
{
    __shared__ unsigned short tile[64 * 72];
    const int t = threadIdx.x;
    const int m0 = blockIdx.x * 64, d0 = blockIdx.y * 64;

#pragma unroll
    for (int r = 0; r < 4; ++r) {
        int idx = r * 256 + t;
        int ml = idx >> 4, dl4 = (idx & 15) * 4;
        float4 v = *(const float4*)(other_feat + (size_t)(m0 + ml) * 256 + d0 + dl4);
        float f = fix_feat[m0 + ml];
        tile[(dl4 + 0) * 72 + ml] = f2bf(v.x * f);
        tile[(dl4 + 1) * 72 + ml] = f2bf(v.y * f);
        tile[(dl4 + 2) * 72 + ml] = f2bf(v.z * f);
        tile[(dl4 + 3) * 72 + ml] = f2bf(v.w * f);
    }
    __syncthreads();
#pragma unroll
    for (int r = 0; r < 8; ++r) {
        int dl = r * 8 + (t >> 5);
        int d = d0 + dl;
        int ml = (t & 31) * 2;
        int e = ml >> 5, s = (ml >> 4) & 1, q = (ml >> 2) & 3, j = ml & 3;
        int pc = e * 32 + q * 8 + s * 4 + j;
        int phys = ((((pc >> 3) + d) & 7) << 3) | (pc & 7);
        unsigned int v0 = tile[dl * 72 + ml];
        unsigned int v1 = tile[dl * 72 + ml + 1];
        *(unsigned int*)(Vt + (size_t)d * M_KV + m0 + phys) = v0 | (v1 << 16);
    }
}

// ---------------------------------------------------------------------------
// Flash attention body — EXACT R4 schedule/register-profile (proven
// spill-free: mask regs live only PV..loop-top) + per-block KV PHASE STAGGER:
// block lx starts its tile loop at tile (lx % iters), wrapping. Co-resident
// blocks issue their 32 KB mask bursts at uniformly spread phases instead of
// lockstep -> steady HBM demand, higher duty cycle. fp32 sum order over KV
// tiles changes (harmless at threshold).
// ESZ = mask element size (4: int32/f32 nonzero; 1: bool/uint8).
// BM=128, K double-buffered, Vt single-buffered, S^T formulation,
// all-16x16x32 MFMA, pc-permuted Vt, no online max. LDS 64 KB -> 2 blk/CU.
// ---------------------------------------------------------------------------
template<int ESZ>
__device__ __forceinline__ void flash_body(
    const unsigned short* __restrict__ Qw, const unsigned short* __restrict__ Kw,
    const unsigned short* __restrict__ Vt, const unsigned int* __restrict__ mask,
    unsigned short* __restrict__ Opart, float* __restrict__ Lpart,
    int nsplit, int lgNs,
    unsigned short* k_lds /* 2 x 64 x 128 */, unsigned short* vt_lds /* 256 x 64 */)
{
    const int L = blockIdx.x + gridDim.x * blockIdx.y;
    const int ly = L & (nsplit - 1);      // L&7 == XCD id under round-robin
    const int lx = L >> lgNs;             // -> per-XCD L2-resident K/V chunk
    const int chunkLen = M_KV >> lgNs;
    const int mBeg = ly * chunkLen;
    const int iters = chunkLen / 64;
    const int phase = lx & (iters - 1);   // per-block start tile (iters is pow2)
    const int tid = threadIdx.x;
    const int wave = tid >> 6, lane = tid & 63, n = lane & 15, quad = lane >> 4;
    const int qrow0 = lx * 128 + wave * 32;
    constexpr float SC = 0.08838834764831845f * 1.4426950408889634f; // scale*log2(e)

    // staggered tile -> column base
    auto mcol = [&](int it) {
        int idx = it + phase;
        if (idx >= iters) idx -= iters;
        return mBeg + idx * 64;
    };

    // Q fragments (rotated layout: unit' = (unit + row) & 15)
    short8 qf[2][4];
#pragma unroll
    for (int qt = 0; qt < 2; ++qt)
#pragma unroll
        for (int db = 0; db < 4; ++db) {
            int row = qrow0 + qt * 16 + n;
            int phys = (db * 4 + quad + row) & 15;
            qf[qt][db] = *(const short8*)(Qw + (size_t)row * DMID + phys * 8);
        }

    floatx4 Oacc[2][16];
#pragma unroll
    for (int qt = 0; qt < 2; ++qt)
#pragma unroll
        for (int dt = 0; dt < 16; ++dt) Oacc[qt][dt] = floatx4{0.f, 0.f, 0.f, 0.f};

    float lrow[2] = {0.f, 0.f};

    // staging invariants
    const unsigned short* kg = Kw + (size_t)(wave * 4 + (lane >> 4)) * DMID + (lane & 15) * 8;
    const unsigned short* vg = Vt + (size_t)(wave * 8 + (lane >> 3)) * M_KV + (lane & 7) * 8;
    unsigned short* vld = &vt_lds[wave * 512];
    const int kqn = quad + n;

    // raw-mask prefetch registers (live only PV..loop-top; compressed before QK)
    uint4    mv4[2][4];   // ESZ==4: 16 elems/lane (cols m0+kvt*16+quad*4+j)
    unsigned mv1[2][4];   // ESZ==1: same cols, 4 bytes per dword

    auto load_mask = [&](int m0l) {
#pragma unroll
        for (int qt = 0; qt < 2; ++qt) {
            const size_t row = (size_t)(qrow0 + qt * 16 + n);
            if constexpr (ESZ == 4) {
                const unsigned* mp = mask + row * M_KV + m0l + quad * 4;
#pragma unroll
                for (int kvt = 0; kvt < 4; ++kvt)
                    mv4[qt][kvt] = *(const uint4*)(mp + kvt * 16);
            } else {
                const unsigned* mp = mask + row * (M_KV / 4) + (m0l >> 2) + quad;
#pragma unroll
                for (int kvt = 0; kvt < 4; ++kvt)
                    mv1[qt][kvt] = mp[kvt * 4];
            }
        }
    };

    // prologue: K(tile 0) DMA into buffer 0, mask(tile 0) prefetch
    {
        const int m0p = mcol(0);
#pragma unroll
        for (int r = 0; r < 4; ++r)
            gl_lds16(kg + (size_t)(m0p + r * 16) * DMID, &k_lds[wave * 512 + r * 2048]);
        load_mask(m0p);
    }

    for (int it = 0; it < iters; ++it) {
        const int m0 = mcol(it);
        const unsigned short* kbuf = k_lds + (it & 1) * 8192;

        __syncthreads();   // drains K(it)+mask(it); separates PV(it-1) reads from Vt(it) writes

        // Vt(it) DMA (drained at mid barrier; overlaps QK+softmax)
#pragma unroll
        for (int r = 0; r < 8; ++r)
            gl_lds16(vg + (size_t)(r * 32) * M_KV + m0, vld + r * 2048);

        // compress mask regs -> 16 predicate bits per lane (bit kvt*4+j)
        unsigned wq[2];
#pragma unroll
        for (int qt = 0; qt < 2; ++qt) {
            unsigned b = 0;
            if constexpr (ESZ == 4) {
#pragma unroll
                for (int kvt = 0; kvt < 4; ++kvt) {
                    const unsigned* c = (const unsigned*)&mv4[qt][kvt];
#pragma unroll
                    for (int j = 0; j < 4; ++j)
                        b |= (c[j] != 0u ? 1u : 0u) << (kvt * 4 + j);
                }
            } else {
#pragma unroll
                for (int kvt = 0; kvt < 4; ++kvt)
                    b |= nz4(mv1[qt][kvt]) << (kvt * 4);
            }
            wq[qt] = b;
        }

        // ---- S^T = K Q^T (kv = 16kvt + 4quad + reg, q = n) ----
        floatx4 ST[4][2];
        __builtin_amdgcn_s_setprio(1);
#pragma unroll
        for (int kvt = 0; kvt < 4; ++kvt) {
            const int rowoff = (kvt * 16 + n) * DMID;
            short8 a0 = *(const short8*)&kbuf[rowoff + (((kqn + 0) & 15) << 3)];
            short8 a1 = *(const short8*)&kbuf[rowoff + (((kqn + 4) & 15) << 3)];
            short8 a2 = *(const short8*)&kbuf[rowoff + (((kqn + 8) & 15) << 3)];
            short8 a3 = *(const short8*)&kbuf[rowoff + (((kqn + 12) & 15) << 3)];
#pragma unroll
            for (int qt = 0; qt < 2; ++qt) {
                floatx4 s = floatx4{0.f, 0.f, 0.f, 0.f};
                s = MFMA32K(a0, qf[qt][0], s);
                s = MFMA32K(a1, qf[qt][1], s);
                s = MFMA32K(a2, qf[qt][2], s);
                s = MFMA32K(a3, qf[qt][3], s);
                ST[kvt][qt] = s;
            }
        }
        __builtin_amdgcn_s_setprio(0);

        // ---- p = exp2(s*SC), 0 where masked; pack to A-frags ----
        short8 pf8[2][2];
#pragma unroll
        for (int qt = 0; qt < 2; ++qt) {
            const unsigned x = wq[qt];
            float lacc = 0.f;
#pragma unroll
            for (int kvt = 0; kvt < 4; ++kvt) {
                int e = kvt >> 1, s = kvt & 1;
                float p[4];
#pragma unroll
                for (int j = 0; j < 4; ++j) {
                    float v = __builtin_amdgcn_exp2f(ST[kvt][qt][j] * SC);
                    p[j] = ((x >> (kvt * 4 + j)) & 1u) ? 0.f : v;
                    lacc += p[j];
                }
                __hip_bfloat162 h0 = __float22bfloat162_rn(make_float2(p[0], p[1]));
                __hip_bfloat162 h1 = __float22bfloat162_rn(make_float2(p[2], p[3]));
                unsigned u0, u1;
                __builtin_memcpy(&u0, &h0, 4);
                __builtin_memcpy(&u1, &h1, 4);
                ((unsigned*)&pf8[qt][e])[s * 2 + 0] = u0;
                ((unsigned*)&pf8[qt][e])[s * 2 + 1] = u1;
            }
            lrow[qt] += lacc;
        }

        __syncthreads();   // drains Vt(it); separates QK reads from K(it+1) writes

        // K(it+1) DMA into other buffer + mask(it+1) prefetch (hide under PV)
        if (it + 1 < iters) {
            const int m1 = mcol(it + 1);
            unsigned short* knext = k_lds + ((it + 1) & 1) * 8192 + wave * 512;
#pragma unroll
            for (int r = 0; r < 4; ++r)
                gl_lds16(kg + (size_t)(m1 + r * 16) * DMID, knext + r * 2048);
            load_mask(m1);
        }

        // ---- O += P V (rotated contiguous b128 from vt_lds) ----
        __builtin_amdgcn_s_setprio(1);
#pragma unroll
        for (int e = 0; e < 2; ++e) {
#pragma unroll
            for (int dt = 0; dt < 16; ++dt) {
                const int vb = (dt * 16 + n) * 64 + (((e * 4 + quad + n) & 7) << 3);
                short8 bv = *(const short8*)&vt_lds[vb];
                Oacc[0][dt] = MFMA32K(pf8[0][e], bv, Oacc[0][dt]);
                Oacc[1][dt] = MFMA32K(pf8[1][e], bv, Oacc[1][dt]);
            }
        }
        __builtin_amdgcn_s_setprio(0);
    }

    // ---- epilogue: bf16 partials + cross-quad l reduction ----
    const size_t obase = (size_t)ly * N_Q * DV;
#pragma unroll
    for (int qt = 0; qt < 2; ++qt)
#pragma unroll
        for (int dt = 0; dt < 16; ++dt)
#pragma unroll
            for (int reg = 0; reg < 4; ++reg) {
                int gr = qrow0 + qt * 16 + quad * 4 + reg;
                Opart[obase + (size_t)gr * DV + dt * 16 + n] = f2bf(Oacc[qt][dt][reg]);
            }
#pragma unroll
    for (int qt = 0; qt < 2; ++qt) {
        float r = lrow[qt];
        r += __shfl_xor(r, 16);
        r += __shfl_xor(r, 32);
        if (quad == 0)
            Lpart[ly * N_Q + qrow0 + qt * 16 + n] = r;
    }
}

// ---------------------------------------------------------------------------
// Flash kernel: in-device mask-dtype detection (element count can't
// distinguish 1B vs 4B storage host-side), then dispatch to matching body.
// Both bodies share the kernel-scope LDS (64 KB -> 2 blocks/CU).
// ---------------------------------------------------------------------------
__global__ __launch_bounds__(256, 2) void flash_kernel(
    const unsigned short* __restrict__ Qw, const unsigned short* __restrict__ Kw,
    const unsigned short* __restrict__ Vt, const unsigned int* __restrict__ mask,
    unsigned short* __restrict__ Opart, float* __restrict__ Lpart,
    int nsplit, int lgNs)
{
    __shared__ __align__(16) unsigned short k_lds[2][64 * 128];  // 2 x 16 KB
    __shared__ __align__(16) unsigned short vt_lds[256 * 64];    // 32 KB

    // dtype detect on first 64 words (L2-hot; identical across waves/blocks):
    // f32 1.0 pattern -> 4-byte; word>1 -> packed uint8; else int32 -> 4-byte
    unsigned w0 = mask[threadIdx.x & 63];
    bool isf = (w0 == 0x3f800000u);
    bool isb = (w0 > 1u) && !isf;
    bool wide = (__ballot(isf) != 0ull) || (__ballot(isb) == 0ull);

    if (wide)
        flash_body<4>(Qw, Kw, Vt, mask, Opart, Lpart, nsplit, lgNs,
                      &k_lds[0][0], vt_lds);
    else
        flash_body<1>(Qw, Kw, Vt, mask, Opart, Lpart, nsplit, lgNs,
                      &k_lds[0][0], vt_lds);
}

// ---------------------------------------------------------------------------
// Combine: out = (sum_c O_c) / (sum_c l_c).
// ---------------------------------------------------------------------------
__global__ __launch_bounds__(256) void combine_kernel(
    const unsigned short* __restrict__ Opart, const float* __restrict__ Lpart,
    float* __restrict__ out, int nsplit)
{
    const int row = blockIdx.x, d = threadIdx.x;
    float L = 0.f, o = 0.f;
    for (int c = 0; c < nsplit; ++c) {
        L += Lpart[c * N_Q + row];
        unsigned int b = Opart[((size_t)c * N_Q + row) * DV + d];
        o += __uint_as_float(b << 16);
    }
    out[(size_t)row * DV + d] = o / L;
}

// ---------------------------------------------------------------------------
extern "C" void kernel_launch(void* const* d_in, const int* in_sizes, int n_in,
                              void* d_out, int out_size, void* d_ws, size_t ws_size,
                              hipStream_t stream)
{
    const float* main_feat  = (const float*)d_in[0];
    const float* other_feat = (const float*)d_in[1];
    const float* fix_feat   = (const float*)d_in[2];
    const void*  mask       = d_in[3];
    const float* Wq         = (const float*)d_in[4];
    const float* bq         = (const float*)d_in[5];
    const float* Wk         = (const float*)d_in[6];
    const float* bk         = (const float*)d_in[7];
    float* out = (float*)d_out;

    char* ws = (char*)d_ws;
    unsigned short* Qw = (unsigned short*)(ws);                         // 2 MB
    unsigned short* Kw = (unsigned short*)(ws + (1ull << 21));          // 2 MB
    unsigned short* Vt = (unsigned short*)(ws + (2ull << 21));          // 4 MB
    float* Lpart = (float*)(ws + (16ull << 20) + 2048);

    const size_t base = (16ull << 20) + 2048;
    auto need = [&](int ns) {
        return base + (size_t)ns * N_Q * 4 + (size_t)ns * N_Q * DV * 2;
    };
    int nsplit = 1, lgNs = 0;
    if (ws_size >= need(8))      { nsplit = 8; lgNs = 3; }
    else if (ws_size >= need(4)) { nsplit = 4; lgNs = 2; }
    else if (ws_size >= need(2)) { nsplit = 2; lgNs = 1; }

    unsigned short* Opart = (unsigned short*)(Lpart + (size_t)nsplit * N_Q);

    hipLaunchKernelGGL(proj_kernel, dim3(128, 2), dim3(256), 0, stream,
                       main_feat, Wq, bq, other_feat, Wk, bk, Qw, Kw);
    hipLaunchKernelGGL(build_vt_kernel, dim3(128, 4), dim3(256), 0, stream,
                       other_feat, fix_feat, Vt);
    hipLaunchKernelGGL(flash_kernel, dim3(64, nsplit), dim3(256), 0, stream,
                       Qw, Kw, Vt, (const unsigned int*)mask, Opart, Lpart, nsplit, lgNs);
    hipLaunchKernelGGL(combine_kernel, dim3(N_Q), dim3(256), 0, stream,
                       Opart, Lpart, out, nsplit);
}